// Round 1
// baseline (392.442 us; speedup 1.0000x reference)
//
#include <hip/hip_runtime.h>
#include <math.h>

#define B      16
#define KN     80000
#define MASKW  32
#define MASKPX 1024
#define NCLS   3
#define BN     95
#define NP     100
#define NCOV   5
#define FW     128
#define FCH    512
#define FPX    16384
#define CIN    515
#define FSTR   516
#define HID    256
#define NBIN   4096
#define CCAP   4096
#define PB     8

// ---- ws layout (float offsets) ----
#define WS_PS0 0
#define WS_PS1 (WS_PS0 + B*MASKPX)                 // 16384
#define WS_U   (WS_PS1 + B*MASKPX)                 // 32768
#define WS_PTS (WS_U + B*KN)                       // 1312768
#define WS_F   (WS_PTS + B*NP*2)                   // 1315968
// total: WS_F + 1600*516 = 2,141,568 floats ~ 8.6 MB

// K1: per-pixel softmax over 3 classes, keep top-2 (descending) probabilities.
__global__ void k_softmax_top2(const float* __restrict__ mask,
                               float* __restrict__ ps0, float* __restrict__ ps1) {
    int i = blockIdx.x * blockDim.x + threadIdx.x;
    if (i >= B * MASKPX) return;
    int b = i >> 10, pix = i & 1023;
    const float* mb = mask + (size_t)b * NCLS * MASKPX + pix;
    float a0 = mb[0], a1 = mb[MASKPX], a2 = mb[2 * MASKPX];
    float m = fmaxf(fmaxf(a0, a1), a2);
    // correctly-rounded fp32 exp via double
    float e0 = (float)exp((double)(a0 - m));
    float e1 = (float)exp((double)(a1 - m));
    float e2 = (float)exp((double)(a2 - m));
    float s = (e0 + e1) + e2;
    float p0 = e0 / s, p1 = e1 / s, p2 = e2 / s;
    float hi  = fmaxf(fmaxf(p0, p1), p2);
    float mid = fmaxf(fminf(p0, p1), fminf(fmaxf(p0, p1), p2));
    ps0[i] = hi;
    ps1[i] = mid;
}

// K2: uncertainty = -(bilin(ps0) - bilin(ps1)) at over_gen points.
// Replicates reference point_sample op order exactly (fp32).
__global__ void k_sample_u(const float* __restrict__ og,
                           const float* __restrict__ ps0, const float* __restrict__ ps1,
                           float* __restrict__ u) {
    int b = blockIdx.y;
    int i = blockIdx.x * blockDim.x + threadIdx.x;
    if (i >= KN) return;
    const float* p = og + ((size_t)b * KN + i) * 2;
    float cx = p[0], cy = p[1];
    float gx = 2.0f * cx - 1.0f, gy = 2.0f * cy - 1.0f;
    float ix = ((gx + 1.0f) * 32.0f - 1.0f) * 0.5f;
    float iy = ((gy + 1.0f) * 32.0f - 1.0f) * 0.5f;
    float x0 = floorf(ix), y0 = floorf(iy);
    float wx1 = ix - x0, wy1 = iy - y0;
    float wx0 = 1.0f - wx1, wy0 = 1.0f - wy1;
    const float* m0 = ps0 + b * MASKPX;
    const float* m1 = ps1 + b * MASKPX;
    float s0 = 0.f, s1 = 0.f;
#define TAP(XC, YC, WV) { \
        float xf = (XC), yf = (YC); \
        float valid = (xf >= 0.f && xf <= 31.f && yf >= 0.f && yf <= 31.f) ? 1.f : 0.f; \
        int xi = (int)fminf(fmaxf(xf, 0.f), 31.f); \
        int yi = (int)fminf(fmaxf(yf, 0.f), 31.f); \
        float w = (WV) * valid; \
        int off = yi * 32 + xi; \
        s0 += m0[off] * w; s1 += m1[off] * w; }
    TAP(x0,        y0,        wx0 * wy0)
    TAP(x0 + 1.0f, y0,        wx1 * wy0)
    TAP(x0,        y0 + 1.0f, wx0 * wy1)
    TAP(x0 + 1.0f, y0 + 1.0f, wx1 * wy1)
#undef TAP
    u[(size_t)b * KN + i] = -(s0 - s1);
}

// K3: per-batch top-95 (value desc, tie -> lower index), then emit points
// (95 importance + 5 coverage) to ws and to d_out points section.
__global__ __launch_bounds__(256) void k_topk(const float* __restrict__ u,
                                              const float* __restrict__ og,
                                              const float* __restrict__ cov,
                                              float* __restrict__ pts_ws,
                                              float* __restrict__ pts_out) {
    int b = blockIdx.x;
    int tid = threadIdx.x;
    __shared__ int   hist[NBIN];
    __shared__ float cv[CCAP];
    __shared__ int   ci[CCAP];
    __shared__ int   s_cnt;
    __shared__ float s_T;
    for (int i = tid; i < NBIN; i += 256) hist[i] = 0;
    if (tid == 0) s_cnt = 0;
    __syncthreads();
    const float* ub = u + (size_t)b * KN;
    for (int i = tid; i < KN; i += 256) {
        float v = ub[i];
        int bin = (int)((v + 1.0f) * 4096.0f);
        bin = bin < 0 ? 0 : (bin > NBIN - 1 ? NBIN - 1 : bin);
        atomicAdd(&hist[bin], 1);
    }
    __syncthreads();
    if (tid == 0) {
        int cum = 0, tb = 0;
        for (int t = NBIN - 1; t >= 0; --t) {
            cum += hist[t];
            if (cum >= BN) { tb = t; break; }
        }
        // one extra bin of margin against binning-rounding mismatch
        s_T = (tb > 0) ? ((float)(tb - 1) * (1.0f / 4096.0f) - 1.0f) : -2.0f;
    }
    __syncthreads();
    float T = s_T;
    for (int i = tid; i < KN; i += 256) {
        float v = ub[i];
        if (v >= T) {
            int pos = atomicAdd(&s_cnt, 1);
            if (pos < CCAP) { cv[pos] = v; ci[pos] = i; }
        }
    }
    __syncthreads();
    int n = s_cnt; if (n > CCAP) n = CCAP;
    for (int i = tid; i < CCAP; i += 256)
        if (i >= n) { cv[i] = -3.0f; ci[i] = 0x7fffffff; }
    __syncthreads();
    // bitonic sort, descending by (value, then lower index first)
    for (int k = 2; k <= CCAP; k <<= 1) {
        for (int j = k >> 1; j > 0; j >>= 1) {
            for (int idx = tid; idx < CCAP; idx += 256) {
                int l = idx ^ j;
                if (l > idx) {
                    float va = cv[idx], vb = cv[l];
                    int ia = ci[idx], ib = ci[l];
                    bool l_first = (vb > va) || (vb == va && ib < ia);
                    bool dirDesc = ((idx & k) == 0);
                    if (l_first == dirDesc) {
                        cv[idx] = vb; cv[l] = va;
                        ci[idx] = ib; ci[l] = ia;
                    }
                }
            }
            __syncthreads();
        }
    }
    if (tid < BN) {
        int gi = ci[tid];
        float px = og[((size_t)b * KN + gi) * 2];
        float py = og[((size_t)b * KN + gi) * 2 + 1];
        int o = (b * NP + tid) * 2;
        pts_ws[o] = px; pts_ws[o + 1] = py;
        pts_out[o] = px; pts_out[o + 1] = py;
    } else if (tid < NP) {
        int j = tid - BN;
        float px = cov[((size_t)b * NCOV + j) * 2];
        float py = cov[((size_t)b * NCOV + j) * 2 + 1];
        int o = (b * NP + tid) * 2;
        pts_ws[o] = px; pts_ws[o + 1] = py;
        pts_out[o] = px; pts_out[o + 1] = py;
    }
}

// K4: gather feat_rep = [coarse(3 from mask) ; fine(512 from feature)] at the 100 points.
__global__ void k_sample_feat(const float* __restrict__ maskp, const float* __restrict__ feat,
                              const float* __restrict__ pts, float* __restrict__ F) {
    int p = blockIdx.x;            // 0..1599
    int b = p / NP;
    float cx = pts[(size_t)p * 2], cy = pts[(size_t)p * 2 + 1];
    float gx = 2.0f * cx - 1.0f, gy = 2.0f * cy - 1.0f;
    // mask grid (W=H=32)
    float ixm = ((gx + 1.0f) * 32.0f - 1.0f) * 0.5f;
    float iym = ((gy + 1.0f) * 32.0f - 1.0f) * 0.5f;
    float x0m = floorf(ixm), y0m = floorf(iym);
    float wx1m = ixm - x0m, wy1m = iym - y0m;
    float wx0m = 1.0f - wx1m, wy0m = 1.0f - wy1m;
    // feature grid (W=H=128)
    float ixf = ((gx + 1.0f) * 128.0f - 1.0f) * 0.5f;
    float iyf = ((gy + 1.0f) * 128.0f - 1.0f) * 0.5f;
    float x0f = floorf(ixf), y0f = floorf(iyf);
    float wx1f = ixf - x0f, wy1f = iyf - y0f;
    float wx0f = 1.0f - wx1f, wy0f = 1.0f - wy1f;

    for (int c = threadIdx.x; c < CIN; c += blockDim.x) {
        float acc = 0.f;
        if (c < 3) {
            const float* img = maskp + ((size_t)b * NCLS + c) * MASKPX;
#define TAPM(XC, YC, WV) { \
            float xf = (XC), yf = (YC); \
            float valid = (xf >= 0.f && xf <= 31.f && yf >= 0.f && yf <= 31.f) ? 1.f : 0.f; \
            int xi = (int)fminf(fmaxf(xf, 0.f), 31.f); \
            int yi = (int)fminf(fmaxf(yf, 0.f), 31.f); \
            acc += img[yi * 32 + xi] * ((WV) * valid); }
            TAPM(x0m,        y0m,        wx0m * wy0m)
            TAPM(x0m + 1.0f, y0m,        wx1m * wy0m)
            TAPM(x0m,        y0m + 1.0f, wx0m * wy1m)
            TAPM(x0m + 1.0f, y0m + 1.0f, wx1m * wy1m)
#undef TAPM
        } else {
            const float* img = feat + ((size_t)b * FCH + (c - 3)) * FPX;
#define TAPF(XC, YC, WV) { \
            float xf = (XC), yf = (YC); \
            float valid = (xf >= 0.f && xf <= 127.f && yf >= 0.f && yf <= 127.f) ? 1.f : 0.f; \
            int xi = (int)fminf(fmaxf(xf, 0.f), 127.f); \
            int yi = (int)fminf(fmaxf(yf, 0.f), 127.f); \
            acc += img[yi * 128 + xi] * ((WV) * valid); }
            TAPF(x0f,        y0f,        wx0f * wy0f)
            TAPF(x0f + 1.0f, y0f,        wx1f * wy0f)
            TAPF(x0f,        y0f + 1.0f, wx0f * wy1f)
            TAPF(x0f + 1.0f, y0f + 1.0f, wx1f * wy1f)
#undef TAPF
        }
        F[(size_t)p * FSTR + c] = acc;
    }
}

// K5: fused 4-layer MLP, PB points per block, 256 threads = one output channel each.
__global__ __launch_bounds__(256) void k_mlp(const float* __restrict__ F,
                                             const float* __restrict__ w1, const float* __restrict__ w2,
                                             const float* __restrict__ w3, const float* __restrict__ w4,
                                             const float* __restrict__ b4, float* __restrict__ rend) {
    __shared__ float Fl[PB][FSTR];
    __shared__ float hA[PB][HID];
    __shared__ float hB[PB][HID];
    int tid = threadIdx.x;
    int p0 = blockIdx.x * PB;
    for (int i = tid; i < PB * CIN; i += 256) {
        int p = i / CIN, c = i % CIN;
        Fl[p][c] = F[(size_t)(p0 + p) * FSTR + c];
    }
    __syncthreads();
    {   // layer 1: 515 -> 256, relu
        int o = tid;
        float acc[PB];
#pragma unroll
        for (int p = 0; p < PB; ++p) acc[p] = 0.f;
        const float* wr = w1 + (size_t)o * CIN;
        for (int c = 0; c < CIN; ++c) {
            float w = wr[c];
#pragma unroll
            for (int p = 0; p < PB; ++p) acc[p] += w * Fl[p][c];
        }
#pragma unroll
        for (int p = 0; p < PB; ++p) hA[p][o] = fmaxf(acc[p], 0.f);
    }
    __syncthreads();
    {   // layer 2: 256 -> 256, relu
        int o = tid;
        float acc[PB];
#pragma unroll
        for (int p = 0; p < PB; ++p) acc[p] = 0.f;
        const float* wr = w2 + (size_t)o * HID;
        for (int c = 0; c < HID; ++c) {
            float w = wr[c];
#pragma unroll
            for (int p = 0; p < PB; ++p) acc[p] += w * hA[p][c];
        }
#pragma unroll
        for (int p = 0; p < PB; ++p) hB[p][o] = fmaxf(acc[p], 0.f);
    }
    __syncthreads();
    {   // layer 3: 256 -> 256, relu
        int o = tid;
        float acc[PB];
#pragma unroll
        for (int p = 0; p < PB; ++p) acc[p] = 0.f;
        const float* wr = w3 + (size_t)o * HID;
        for (int c = 0; c < HID; ++c) {
            float w = wr[c];
#pragma unroll
            for (int p = 0; p < PB; ++p) acc[p] += w * hB[p][c];
        }
#pragma unroll
        for (int p = 0; p < PB; ++p) hA[p][o] = fmaxf(acc[p], 0.f);
    }
    __syncthreads();
    if (tid < 3 * PB) {  // layer 4: 256 -> 3, + b4
        int o = tid % 3, p = tid / 3;
        float acc = 0.f;
        const float* wr = w4 + (size_t)o * HID;
        for (int c = 0; c < HID; ++c) acc += wr[c] * hA[p][c];
        acc += b4[o];
        int gp = p0 + p;
        int b = gp / NP, n = gp % NP;
        rend[(size_t)b * (NCLS * NP) + o * NP + n] = acc;
    }
}

extern "C" void kernel_launch(void* const* d_in, const int* in_sizes, int n_in,
                              void* d_out, int out_size, void* d_ws, size_t ws_size,
                              hipStream_t stream) {
    // inputs: 0:x(unused) 1:feature 2:mask 3:over_gen 4:coverage 5:w1 6:w2 7:w3 8:w4 9:b4
    const float* feature  = (const float*)d_in[1];
    const float* mask     = (const float*)d_in[2];
    const float* over_gen = (const float*)d_in[3];
    const float* coverage = (const float*)d_in[4];
    const float* w1 = (const float*)d_in[5];
    const float* w2 = (const float*)d_in[6];
    const float* w3 = (const float*)d_in[7];
    const float* w4 = (const float*)d_in[8];
    const float* b4 = (const float*)d_in[9];
    float* out = (float*)d_out;
    float* ws  = (float*)d_ws;

    float* ps0 = ws + WS_PS0;
    float* ps1 = ws + WS_PS1;
    float* uws = ws + WS_U;
    float* pts = ws + WS_PTS;
    float* Fws = ws + WS_F;

    // out layout: rend[4800] | points[3200] | mask[49152]
    float* out_rend = out;
    float* out_pts  = out + 4800;
    float* out_mask = out + 8000;

    k_softmax_top2<<<(B * MASKPX + 255) / 256, 256, 0, stream>>>(mask, ps0, ps1);
    dim3 g2((KN + 255) / 256, B);
    k_sample_u<<<g2, 256, 0, stream>>>(over_gen, ps0, ps1, uws);
    k_topk<<<B, 256, 0, stream>>>(uws, over_gen, coverage, pts, out_pts);
    k_sample_feat<<<B * NP, 128, 0, stream>>>(mask, feature, pts, Fws);
    k_mlp<<<(B * NP) / PB, 256, 0, stream>>>(Fws, w1, w2, w3, w4, b4, out_rend);
    hipMemcpyAsync(out_mask, mask, (size_t)B * NCLS * MASKPX * sizeof(float),
                   hipMemcpyDeviceToDevice, stream);
}

// Round 2
// 185.977 us; speedup vs baseline: 2.1102x; 2.1102x over previous
//
#include <hip/hip_runtime.h>
#include <math.h>

#define B      16
#define KN     80000
#define MASKW  32
#define MASKPX 1024
#define NCLS   3
#define BN     95
#define NP     100
#define NCOV   5
#define FW     128
#define FCH    512
#define FPX    16384
#define CIN    515
#define FSTR   516
#define HID    256
#define NBIN   4096
#define CCAP   2048
#define PB     8

// ---- ws layout (float offsets) ----
#define WS_PS0 0
#define WS_PS1 (WS_PS0 + B*MASKPX)
#define WS_U   (WS_PS1 + B*MASKPX)
#define WS_PTS (WS_U + B*KN)
#define WS_F   (WS_PTS + B*NP*2)
#define WS_WT1 (WS_F + B*NP*FSTR)
#define WS_WT2 (WS_WT1 + FSTR*HID)
#define WS_WT3 (WS_WT2 + HID*HID)
// end: WS_WT3 + HID*HID  (~2.4 M floats, ~9.6 MB)

// K0: transpose weights into [c][o] layout (c padded to FSTR for w1).
__global__ void k_tw(const float* __restrict__ w1, const float* __restrict__ w2,
                     const float* __restrict__ w3,
                     float* __restrict__ wt1, float* __restrict__ wt2,
                     float* __restrict__ wt3) {
    int i = blockIdx.x * blockDim.x + threadIdx.x;
    if (i < FSTR * HID) {
        int c = i >> 8, o = i & 255;
        wt1[i] = (c < CIN) ? w1[o * CIN + c] : 0.0f;
        return;
    }
    int j = i - FSTR * HID;
    if (j < HID * HID) {
        int c = j >> 8, o = j & 255;
        wt2[j] = w2[o * HID + c];
        return;
    }
    int k = j - HID * HID;
    if (k < HID * HID) {
        int c = k >> 8, o = k & 255;
        wt3[k] = w3[o * HID + c];
    }
}

// K1: per-pixel softmax over 3 classes, keep top-2 (descending) probabilities.
__global__ void k_softmax_top2(const float* __restrict__ mask,
                               float* __restrict__ ps0, float* __restrict__ ps1) {
    int i = blockIdx.x * blockDim.x + threadIdx.x;
    if (i >= B * MASKPX) return;
    int b = i >> 10, pix = i & 1023;
    const float* mb = mask + (size_t)b * NCLS * MASKPX + pix;
    float a0 = mb[0], a1 = mb[MASKPX], a2 = mb[2 * MASKPX];
    float m = fmaxf(fmaxf(a0, a1), a2);
    float e0 = (float)exp((double)(a0 - m));
    float e1 = (float)exp((double)(a1 - m));
    float e2 = (float)exp((double)(a2 - m));
    float s = (e0 + e1) + e2;
    float p0 = e0 / s, p1 = e1 / s, p2 = e2 / s;
    float hi  = fmaxf(fmaxf(p0, p1), p2);
    float mid = fmaxf(fminf(p0, p1), fminf(fmaxf(p0, p1), p2));
    ps0[i] = hi;
    ps1[i] = mid;
}

// K2: uncertainty = -(bilin(ps0) - bilin(ps1)) at over_gen points.
// Replicates reference point_sample op order exactly (fp32).
__global__ void k_sample_u(const float* __restrict__ og,
                           const float* __restrict__ ps0, const float* __restrict__ ps1,
                           float* __restrict__ u) {
    int b = blockIdx.y;
    int i = blockIdx.x * blockDim.x + threadIdx.x;
    if (i >= KN) return;
    const float* p = og + ((size_t)b * KN + i) * 2;
    float cx = p[0], cy = p[1];
    float gx = 2.0f * cx - 1.0f, gy = 2.0f * cy - 1.0f;
    float ix = ((gx + 1.0f) * 32.0f - 1.0f) * 0.5f;
    float iy = ((gy + 1.0f) * 32.0f - 1.0f) * 0.5f;
    float x0 = floorf(ix), y0 = floorf(iy);
    float wx1 = ix - x0, wy1 = iy - y0;
    float wx0 = 1.0f - wx1, wy0 = 1.0f - wy1;
    const float* m0 = ps0 + b * MASKPX;
    const float* m1 = ps1 + b * MASKPX;
    float s0 = 0.f, s1 = 0.f;
#define TAP(XC, YC, WV) { \
        float xf = (XC), yf = (YC); \
        float valid = (xf >= 0.f && xf <= 31.f && yf >= 0.f && yf <= 31.f) ? 1.f : 0.f; \
        int xi = (int)fminf(fmaxf(xf, 0.f), 31.f); \
        int yi = (int)fminf(fmaxf(yf, 0.f), 31.f); \
        float w = (WV) * valid; \
        int off = yi * 32 + xi; \
        s0 += m0[off] * w; s1 += m1[off] * w; }
    TAP(x0,        y0,        wx0 * wy0)
    TAP(x0 + 1.0f, y0,        wx1 * wy0)
    TAP(x0,        y0 + 1.0f, wx0 * wy1)
    TAP(x0 + 1.0f, y0 + 1.0f, wx1 * wy1)
#undef TAP
    u[(size_t)b * KN + i] = -(s0 - s1);
}

// K3: per-batch top-95 (value desc, tie -> lower index), then emit points.
__global__ __launch_bounds__(1024) void k_topk(const float* __restrict__ u,
                                               const float* __restrict__ og,
                                               const float* __restrict__ cov,
                                               float* __restrict__ pts_ws,
                                               float* __restrict__ pts_out) {
    int b = blockIdx.x;
    int tid = threadIdx.x;
    __shared__ int   hist[NBIN];
    __shared__ float cv[CCAP];
    __shared__ int   ci[CCAP];
    __shared__ int   s_cnt;
    __shared__ float s_T;
    for (int i = tid; i < NBIN; i += 1024) hist[i] = 0;
    if (tid == 0) s_cnt = 0;
    __syncthreads();
    const float* ub = u + (size_t)b * KN;
    for (int i = tid; i < KN; i += 1024) {
        float v = ub[i];
        int bin = (int)((v + 1.0f) * 4096.0f);
        bin = bin < 0 ? 0 : (bin > NBIN - 1 ? NBIN - 1 : bin);
        atomicAdd(&hist[bin], 1);
    }
    __syncthreads();
    if (tid == 0) {
        int cum = 0, tb = 0;
        for (int t = NBIN - 1; t >= 0; --t) {
            cum += hist[t];
            if (cum >= BN) { tb = t; break; }
        }
        // one extra bin of margin against binning-rounding mismatch
        s_T = (tb > 0) ? ((float)(tb - 1) * (1.0f / 4096.0f) - 1.0f) : -2.0f;
    }
    __syncthreads();
    float T = s_T;
    for (int i = tid; i < KN; i += 1024) {
        float v = ub[i];
        if (v >= T) {
            int pos = atomicAdd(&s_cnt, 1);
            if (pos < CCAP) { cv[pos] = v; ci[pos] = i; }
        }
    }
    __syncthreads();
    int n = s_cnt; if (n > CCAP) n = CCAP;
    for (int i = tid; i < CCAP; i += 1024)
        if (i >= n) { cv[i] = -3.0f; ci[i] = 0x7fffffff; }
    __syncthreads();
    // bitonic sort, descending by (value, then lower index first)
    for (int k = 2; k <= CCAP; k <<= 1) {
        for (int j = k >> 1; j > 0; j >>= 1) {
            for (int idx = tid; idx < CCAP; idx += 1024) {
                int l = idx ^ j;
                if (l > idx) {
                    float va = cv[idx], vb = cv[l];
                    int ia = ci[idx], ib = ci[l];
                    bool l_first = (vb > va) || (vb == va && ib < ia);
                    bool dirDesc = ((idx & k) == 0);
                    if (l_first == dirDesc) {
                        cv[idx] = vb; cv[l] = va;
                        ci[idx] = ib; ci[l] = ia;
                    }
                }
            }
            __syncthreads();
        }
    }
    if (tid < BN) {
        int gi = ci[tid];
        float px = og[((size_t)b * KN + gi) * 2];
        float py = og[((size_t)b * KN + gi) * 2 + 1];
        int o = (b * NP + tid) * 2;
        pts_ws[o] = px; pts_ws[o + 1] = py;
        pts_out[o] = px; pts_out[o + 1] = py;
    } else if (tid < NP) {
        int j = tid - BN;
        float px = cov[((size_t)b * NCOV + j) * 2];
        float py = cov[((size_t)b * NCOV + j) * 2 + 1];
        int o = (b * NP + tid) * 2;
        pts_ws[o] = px; pts_ws[o + 1] = py;
        pts_out[o] = px; pts_out[o + 1] = py;
    }
}

// K4: gather feat_rep = [coarse(3 from mask) ; fine(512 from feature) ; 0 pad].
__global__ __launch_bounds__(256) void k_sample_feat(const float* __restrict__ maskp,
                                                     const float* __restrict__ feat,
                                                     const float* __restrict__ pts,
                                                     float* __restrict__ F) {
    int p = blockIdx.x;            // 0..1599
    int b = p / NP;
    float cx = pts[(size_t)p * 2], cy = pts[(size_t)p * 2 + 1];
    float gx = 2.0f * cx - 1.0f, gy = 2.0f * cy - 1.0f;
    float ixm = ((gx + 1.0f) * 32.0f - 1.0f) * 0.5f;
    float iym = ((gy + 1.0f) * 32.0f - 1.0f) * 0.5f;
    float x0m = floorf(ixm), y0m = floorf(iym);
    float wx1m = ixm - x0m, wy1m = iym - y0m;
    float wx0m = 1.0f - wx1m, wy0m = 1.0f - wy1m;
    float ixf = ((gx + 1.0f) * 128.0f - 1.0f) * 0.5f;
    float iyf = ((gy + 1.0f) * 128.0f - 1.0f) * 0.5f;
    float x0f = floorf(ixf), y0f = floorf(iyf);
    float wx1f = ixf - x0f, wy1f = iyf - y0f;
    float wx0f = 1.0f - wx1f, wy0f = 1.0f - wy1f;

    for (int c = threadIdx.x; c < FSTR; c += blockDim.x) {
        float acc = 0.f;
        if (c < 3) {
            const float* img = maskp + ((size_t)b * NCLS + c) * MASKPX;
#define TAPM(XC, YC, WV) { \
            float xf = (XC), yf = (YC); \
            float valid = (xf >= 0.f && xf <= 31.f && yf >= 0.f && yf <= 31.f) ? 1.f : 0.f; \
            int xi = (int)fminf(fmaxf(xf, 0.f), 31.f); \
            int yi = (int)fminf(fmaxf(yf, 0.f), 31.f); \
            acc += img[yi * 32 + xi] * ((WV) * valid); }
            TAPM(x0m,        y0m,        wx0m * wy0m)
            TAPM(x0m + 1.0f, y0m,        wx1m * wy0m)
            TAPM(x0m,        y0m + 1.0f, wx0m * wy1m)
            TAPM(x0m + 1.0f, y0m + 1.0f, wx1m * wy1m)
#undef TAPM
        } else if (c < CIN) {
            const float* img = feat + ((size_t)b * FCH + (c - 3)) * FPX;
#define TAPF(XC, YC, WV) { \
            float xf = (XC), yf = (YC); \
            float valid = (xf >= 0.f && xf <= 127.f && yf >= 0.f && yf <= 127.f) ? 1.f : 0.f; \
            int xi = (int)fminf(fmaxf(xf, 0.f), 127.f); \
            int yi = (int)fminf(fmaxf(yf, 0.f), 127.f); \
            acc += img[yi * 128 + xi] * ((WV) * valid); }
            TAPF(x0f,        y0f,        wx0f * wy0f)
            TAPF(x0f + 1.0f, y0f,        wx1f * wy0f)
            TAPF(x0f,        y0f + 1.0f, wx0f * wy1f)
            TAPF(x0f + 1.0f, y0f + 1.0f, wx1f * wy1f)
#undef TAPF
        }  // c == 515: pad channel, stays 0
        F[(size_t)p * FSTR + c] = acc;
    }
}

// K5: fused 4-layer MLP, PB points per block; weights pre-transposed [c][o]
// so each wave-load of weights is 1 KB coalesced; F read as LDS float4 broadcast.
__global__ __launch_bounds__(256) void k_mlp(const float* __restrict__ F,
                                             const float* __restrict__ wt1,
                                             const float* __restrict__ wt2,
                                             const float* __restrict__ wt3,
                                             const float* __restrict__ w4,
                                             const float* __restrict__ b4,
                                             float* __restrict__ rend) {
    __shared__ float Fl[PB][FSTR];
    __shared__ float hA[PB][HID];
    __shared__ float hB[PB][HID];
    int tid = threadIdx.x;
    int p0 = blockIdx.x * PB;
    {   // coalesced float4 load of 8 x 516 inputs
        const float4* src = (const float4*)(F + (size_t)p0 * FSTR);
        float4* dst = (float4*)&Fl[0][0];
        for (int i = tid; i < PB * FSTR / 4; i += 256) dst[i] = src[i];
    }
    __syncthreads();
    {   // layer 1: 515(+1 pad) -> 256, relu
        int o = tid;
        float acc[PB];
#pragma unroll
        for (int p = 0; p < PB; ++p) acc[p] = 0.f;
        for (int c4 = 0; c4 < FSTR / 4; ++c4) {
            float wa = wt1[(c4 * 4 + 0) * HID + o];
            float wb = wt1[(c4 * 4 + 1) * HID + o];
            float wc = wt1[(c4 * 4 + 2) * HID + o];
            float wd = wt1[(c4 * 4 + 3) * HID + o];
#pragma unroll
            for (int p = 0; p < PB; ++p) {
                float4 f = *(const float4*)&Fl[p][c4 * 4];
                acc[p] = fmaf(wa, f.x, acc[p]);
                acc[p] = fmaf(wb, f.y, acc[p]);
                acc[p] = fmaf(wc, f.z, acc[p]);
                acc[p] = fmaf(wd, f.w, acc[p]);
            }
        }
#pragma unroll
        for (int p = 0; p < PB; ++p) hA[p][o] = fmaxf(acc[p], 0.f);
    }
    __syncthreads();
    {   // layer 2: 256 -> 256, relu
        int o = tid;
        float acc[PB];
#pragma unroll
        for (int p = 0; p < PB; ++p) acc[p] = 0.f;
        for (int c4 = 0; c4 < HID / 4; ++c4) {
            float wa = wt2[(c4 * 4 + 0) * HID + o];
            float wb = wt2[(c4 * 4 + 1) * HID + o];
            float wc = wt2[(c4 * 4 + 2) * HID + o];
            float wd = wt2[(c4 * 4 + 3) * HID + o];
#pragma unroll
            for (int p = 0; p < PB; ++p) {
                float4 f = *(const float4*)&hA[p][c4 * 4];
                acc[p] = fmaf(wa, f.x, acc[p]);
                acc[p] = fmaf(wb, f.y, acc[p]);
                acc[p] = fmaf(wc, f.z, acc[p]);
                acc[p] = fmaf(wd, f.w, acc[p]);
            }
        }
#pragma unroll
        for (int p = 0; p < PB; ++p) hB[p][o] = fmaxf(acc[p], 0.f);
    }
    __syncthreads();
    {   // layer 3: 256 -> 256, relu
        int o = tid;
        float acc[PB];
#pragma unroll
        for (int p = 0; p < PB; ++p) acc[p] = 0.f;
        for (int c4 = 0; c4 < HID / 4; ++c4) {
            float wa = wt3[(c4 * 4 + 0) * HID + o];
            float wb = wt3[(c4 * 4 + 1) * HID + o];
            float wc = wt3[(c4 * 4 + 2) * HID + o];
            float wd = wt3[(c4 * 4 + 3) * HID + o];
#pragma unroll
            for (int p = 0; p < PB; ++p) {
                float4 f = *(const float4*)&hB[p][c4 * 4];
                acc[p] = fmaf(wa, f.x, acc[p]);
                acc[p] = fmaf(wb, f.y, acc[p]);
                acc[p] = fmaf(wc, f.z, acc[p]);
                acc[p] = fmaf(wd, f.w, acc[p]);
            }
        }
#pragma unroll
        for (int p = 0; p < PB; ++p) hA[p][o] = fmaxf(acc[p], 0.f);
    }
    __syncthreads();
    if (tid < 3 * PB) {  // layer 4: 256 -> 3, + b4
        int o = tid % 3, p = tid / 3;
        float acc = 0.f;
        const float* wr = w4 + (size_t)o * HID;
        for (int c = 0; c < HID; ++c) acc += wr[c] * hA[p][c];
        acc += b4[o];
        int gp = p0 + p;
        int b = gp / NP, n = gp % NP;
        rend[(size_t)b * (NCLS * NP) + o * NP + n] = acc;
    }
}

extern "C" void kernel_launch(void* const* d_in, const int* in_sizes, int n_in,
                              void* d_out, int out_size, void* d_ws, size_t ws_size,
                              hipStream_t stream) {
    // inputs: 0:x(unused) 1:feature 2:mask 3:over_gen 4:coverage 5:w1 6:w2 7:w3 8:w4 9:b4
    const float* feature  = (const float*)d_in[1];
    const float* mask     = (const float*)d_in[2];
    const float* over_gen = (const float*)d_in[3];
    const float* coverage = (const float*)d_in[4];
    const float* w1 = (const float*)d_in[5];
    const float* w2 = (const float*)d_in[6];
    const float* w3 = (const float*)d_in[7];
    const float* w4 = (const float*)d_in[8];
    const float* b4 = (const float*)d_in[9];
    float* out = (float*)d_out;
    float* ws  = (float*)d_ws;

    float* ps0 = ws + WS_PS0;
    float* ps1 = ws + WS_PS1;
    float* uws = ws + WS_U;
    float* pts = ws + WS_PTS;
    float* Fws = ws + WS_F;
    float* wt1 = ws + WS_WT1;
    float* wt2 = ws + WS_WT2;
    float* wt3 = ws + WS_WT3;

    // out layout: rend[4800] | points[3200] | mask[49152]
    float* out_rend = out;
    float* out_pts  = out + 4800;
    float* out_mask = out + 8000;

    int ntw = FSTR * HID + 2 * HID * HID;
    k_tw<<<(ntw + 255) / 256, 256, 0, stream>>>(w1, w2, w3, wt1, wt2, wt3);
    k_softmax_top2<<<(B * MASKPX + 255) / 256, 256, 0, stream>>>(mask, ps0, ps1);
    dim3 g2((KN + 255) / 256, B);
    k_sample_u<<<g2, 256, 0, stream>>>(over_gen, ps0, ps1, uws);
    k_topk<<<B, 1024, 0, stream>>>(uws, over_gen, coverage, pts, out_pts);
    k_sample_feat<<<B * NP, 256, 0, stream>>>(mask, feature, pts, Fws);
    k_mlp<<<(B * NP) / PB, 256, 0, stream>>>(Fws, wt1, wt2, wt3, w4, b4, out_rend);
    hipMemcpyAsync(out_mask, mask, (size_t)B * NCLS * MASKPX * sizeof(float),
                   hipMemcpyDeviceToDevice, stream);
}

// Round 3
// 172.650 us; speedup vs baseline: 2.2730x; 1.0772x over previous
//
#include <hip/hip_runtime.h>
#include <math.h>

#define B      16
#define KN     80000
#define MASKW  32
#define MASKPX 1024
#define NCLS   3
#define BN     95
#define NP     100
#define NCOV   5
#define FW     128
#define FCH    512
#define FPX    16384
#define CIN    515
#define FSTR   516
#define HID    256
#define NBIN   4096
#define CCAP   2048
#define PB     8

#define NTW    (FSTR*HID + HID*HID + HID*HID)   // 263168
#define NMASK  (B*NCLS*MASKPX)                  // 49152
#define PREP_TOT (NTW + NMASK)                  // 312320 = 305*1024
#define SEL_B  16
#define GRID_FRONT (SEL_B + (PREP_TOT + 1023)/1024)

// ---- ws layout (float offsets) ----
#define WS_U   0
#define WS_PTS (WS_U + B*KN)
#define WS_WT1 (WS_PTS + B*NP*2)
#define WS_WT2 (WS_WT1 + FSTR*HID)
#define WS_WT3 (WS_WT2 + HID*HID)
// end ~1.55 M floats (~6.2 MB)

// K_FRONT: blocks 0..15 = fused per-batch point selection
//          blocks 16+   = weight transpose + mask passthrough
__global__ __launch_bounds__(1024) void k_front(
        const float* __restrict__ mask, const float* __restrict__ og,
        const float* __restrict__ cov,
        const float* __restrict__ w1, const float* __restrict__ w2,
        const float* __restrict__ w3,
        float* __restrict__ uws, float* __restrict__ pts_ws,
        float* __restrict__ pts_out,
        float* __restrict__ wt1, float* __restrict__ wt2, float* __restrict__ wt3,
        float* __restrict__ out_mask) {
    __shared__ float ps0[MASKPX];
    __shared__ float ps1[MASKPX];
    __shared__ int   hist[NBIN];
    __shared__ float cv[CCAP];
    __shared__ int   ci[CCAP];
    __shared__ int   s_cnt;
    __shared__ float s_T;
    int tid = threadIdx.x;

    if (blockIdx.x >= SEL_B) {
        // ---- prep path: elementwise ----
        int j = (blockIdx.x - SEL_B) * 1024 + tid;
        if (j < FSTR * HID) {
            int c = j >> 8, o = j & 255;
            wt1[j] = (c < CIN) ? w1[o * CIN + c] : 0.0f;
            return;
        }
        j -= FSTR * HID;
        if (j < HID * HID) {
            int c = j >> 8, o = j & 255;
            wt2[j] = w2[o * HID + c];
            return;
        }
        j -= HID * HID;
        if (j < HID * HID) {
            int c = j >> 8, o = j & 255;
            wt3[j] = w3[o * HID + c];
            return;
        }
        j -= HID * HID;
        if (j < NMASK) out_mask[j] = mask[j];
        return;
    }

    // ---- select path, batch b ----
    int b = blockIdx.x;
    // softmax top-2 into LDS (identical fp op sequence to prior rounds)
    for (int pix = tid; pix < MASKPX; pix += 1024) {
        const float* mb = mask + (size_t)b * NCLS * MASKPX + pix;
        float a0 = mb[0], a1 = mb[MASKPX], a2 = mb[2 * MASKPX];
        float m = fmaxf(fmaxf(a0, a1), a2);
        float e0 = (float)exp((double)(a0 - m));
        float e1 = (float)exp((double)(a1 - m));
        float e2 = (float)exp((double)(a2 - m));
        float s = (e0 + e1) + e2;
        float p0 = e0 / s, p1 = e1 / s, p2 = e2 / s;
        float hi  = fmaxf(fmaxf(p0, p1), p2);
        float mid = fmaxf(fminf(p0, p1), fminf(fmaxf(p0, p1), p2));
        ps0[pix] = hi;
        ps1[pix] = mid;
    }
    for (int i = tid; i < NBIN; i += 1024) hist[i] = 0;
    if (tid == 0) s_cnt = 0;
    __syncthreads();

    // u + histogram pass (u op sequence identical to prior k_sample_u)
    float* ub = uws + (size_t)b * KN;
    const float2* ogb = (const float2*)(og + (size_t)b * KN * 2);
    for (int i = tid; i < KN; i += 1024) {
        float2 q = ogb[i];
        float cx = q.x, cy = q.y;
        float gx = 2.0f * cx - 1.0f, gy = 2.0f * cy - 1.0f;
        float ix = ((gx + 1.0f) * 32.0f - 1.0f) * 0.5f;
        float iy = ((gy + 1.0f) * 32.0f - 1.0f) * 0.5f;
        float x0 = floorf(ix), y0 = floorf(iy);
        float wx1 = ix - x0, wy1 = iy - y0;
        float wx0 = 1.0f - wx1, wy0 = 1.0f - wy1;
        float s0 = 0.f, s1 = 0.f;
#define TAP(XC, YC, WV) { \
        float xf = (XC), yf = (YC); \
        float valid = (xf >= 0.f && xf <= 31.f && yf >= 0.f && yf <= 31.f) ? 1.f : 0.f; \
        int xi = (int)fminf(fmaxf(xf, 0.f), 31.f); \
        int yi = (int)fminf(fmaxf(yf, 0.f), 31.f); \
        float w = (WV) * valid; \
        int off = yi * 32 + xi; \
        s0 += ps0[off] * w; s1 += ps1[off] * w; }
        TAP(x0,        y0,        wx0 * wy0)
        TAP(x0 + 1.0f, y0,        wx1 * wy0)
        TAP(x0,        y0 + 1.0f, wx0 * wy1)
        TAP(x0 + 1.0f, y0 + 1.0f, wx1 * wy1)
#undef TAP
        float v = -(s0 - s1);
        ub[i] = v;
        int bin = (int)((v + 1.0f) * 4096.0f);
        bin = bin < 0 ? 0 : (bin > NBIN - 1 ? NBIN - 1 : bin);
        atomicAdd(&hist[bin], 1);
    }
    __syncthreads();

    // two-level wave-parallel suffix scan to find threshold bin tb
    if (tid < 64) {
        int sup = 0;
#pragma unroll
        for (int j = 0; j < 64; ++j) sup += hist[(tid << 6) + j];
        int cum = sup;                     // suffix sum over superbins
#pragma unroll
        for (int d = 1; d < 64; d <<= 1) {
            int o = __shfl_down(cum, d, 64);
            if (tid + d < 64) cum += o;
        }
        unsigned long long m1 = __ballot(cum >= BN);
        int SB = 63 - __builtin_clzll(m1);
        int lane2 = (SB + 1) & 63;
        int above = __shfl(cum, lane2, 64);
        if (SB == 63) above = 0;
        int h = hist[(SB << 6) + tid];
        int cumf = h;
#pragma unroll
        for (int d = 1; d < 64; d <<= 1) {
            int o = __shfl_down(cumf, d, 64);
            if (tid + d < 64) cumf += o;
        }
        unsigned long long m2 = __ballot(cumf + above >= BN);
        int t = 63 - __builtin_clzll(m2);
        int tb = (SB << 6) + t;
        if (tid == 0)
            s_T = (tb > 0) ? ((float)(tb - 1) * (1.0f / 4096.0f) - 1.0f) : -2.0f;
    }
    __syncthreads();

    // collect candidates >= T (u re-read, L2-hot)
    float T = s_T;
    for (int i = tid; i < KN; i += 1024) {
        float v = ub[i];
        if (v >= T) {
            int pos = atomicAdd(&s_cnt, 1);
            if (pos < CCAP) { cv[pos] = v; ci[pos] = i; }
        }
    }
    __syncthreads();
    int n = s_cnt; if (n > CCAP) n = CCAP;
    int M = 128; while (M < n) M <<= 1;       // dynamic sort size (uniform)
    for (int i = tid; i < M; i += 1024)
        if (i >= n) { cv[i] = -3.0f; ci[i] = 0x7fffffff; }
    __syncthreads();
    // bitonic sort: descending by (value, then lower index first)
    for (int k = 2; k <= M; k <<= 1) {
        for (int j = k >> 1; j > 0; j >>= 1) {
            for (int idx = tid; idx < M; idx += 1024) {
                int l = idx ^ j;
                if (l > idx) {
                    float va = cv[idx], vb = cv[l];
                    int ia = ci[idx], ib = ci[l];
                    bool l_first = (vb > va) || (vb == va && ib < ia);
                    bool dirDesc = ((idx & k) == 0);
                    if (l_first == dirDesc) {
                        cv[idx] = vb; cv[l] = va;
                        ci[idx] = ib; ci[l] = ia;
                    }
                }
            }
            __syncthreads();
        }
    }
    if (tid < BN) {
        int gi = ci[tid];
        float px = og[((size_t)b * KN + gi) * 2];
        float py = og[((size_t)b * KN + gi) * 2 + 1];
        int o = (b * NP + tid) * 2;
        pts_ws[o] = px; pts_ws[o + 1] = py;
        pts_out[o] = px; pts_out[o + 1] = py;
    } else if (tid < NP) {
        int j = tid - BN;
        float px = cov[((size_t)b * NCOV + j) * 2];
        float py = cov[((size_t)b * NCOV + j) * 2 + 1];
        int o = (b * NP + tid) * 2;
        pts_ws[o] = px; pts_ws[o + 1] = py;
        pts_out[o] = px; pts_out[o + 1] = py;
    }
}

// K_BACK: fused gather (coarse from mask, fine from feature) + 4-layer MLP.
__global__ __launch_bounds__(256) void k_back(
        const float* __restrict__ maskp, const float* __restrict__ feat,
        const float* __restrict__ pts,
        const float* __restrict__ wt1, const float* __restrict__ wt2,
        const float* __restrict__ wt3, const float* __restrict__ w4,
        const float* __restrict__ b4, float* __restrict__ rend) {
    __shared__ float Fl[PB][FSTR];
    __shared__ float hA[PB][HID];
    __shared__ float hB[PB][HID];
    __shared__ float pp[PB][8];
    int tid = threadIdx.x;
    int p0 = blockIdx.x * PB;

    if (tid < PB) {   // per-point sampling params
        int gp = p0 + tid;
        float cx = pts[(size_t)gp * 2], cy = pts[(size_t)gp * 2 + 1];
        float gx = 2.0f * cx - 1.0f, gy = 2.0f * cy - 1.0f;
        float ixf = ((gx + 1.0f) * 128.0f - 1.0f) * 0.5f;
        float iyf = ((gy + 1.0f) * 128.0f - 1.0f) * 0.5f;
        float x0f = floorf(ixf), y0f = floorf(iyf);
        pp[tid][0] = x0f; pp[tid][1] = y0f;
        pp[tid][2] = ixf - x0f; pp[tid][3] = iyf - y0f;
        float ixm = ((gx + 1.0f) * 32.0f - 1.0f) * 0.5f;
        float iym = ((gy + 1.0f) * 32.0f - 1.0f) * 0.5f;
        float x0m = floorf(ixm), y0m = floorf(iym);
        pp[tid][4] = x0m; pp[tid][5] = y0m;
        pp[tid][6] = ixm - x0m; pp[tid][7] = iym - y0m;
    }
    __syncthreads();

    if (tid < PB * 4) {   // coarse channels + pad
        int p = tid >> 2, c = tid & 3;
        if (c < 3) {
            int gp = p0 + p, b = gp / NP;
            float x0m = pp[p][4], y0m = pp[p][5];
            float wx1m = pp[p][6], wy1m = pp[p][7];
            float wx0m = 1.0f - wx1m, wy0m = 1.0f - wy1m;
            const float* img = maskp + ((size_t)b * NCLS + c) * MASKPX;
            float acc = 0.f;
#define TAPM(XC, YC, WV) { \
            float xf = (XC), yf = (YC); \
            float valid = (xf >= 0.f && xf <= 31.f && yf >= 0.f && yf <= 31.f) ? 1.f : 0.f; \
            int xi = (int)fminf(fmaxf(xf, 0.f), 31.f); \
            int yi = (int)fminf(fmaxf(yf, 0.f), 31.f); \
            acc += img[yi * 32 + xi] * ((WV) * valid); }
            TAPM(x0m,        y0m,        wx0m * wy0m)
            TAPM(x0m + 1.0f, y0m,        wx1m * wy0m)
            TAPM(x0m,        y0m + 1.0f, wx0m * wy1m)
            TAPM(x0m + 1.0f, y0m + 1.0f, wx1m * wy1m)
#undef TAPM
            Fl[p][c] = acc;
        } else {
            Fl[p][CIN] = 0.0f;   // pad channel
        }
    }

    // fine channels: 8 pts x 512 ch = 16 per thread, 4 independent loads each
#pragma unroll 4
    for (int i = tid; i < PB * FCH; i += 256) {
        int p = i >> 9, c = i & 511;
        int gp = p0 + p, b = gp / NP;
        float x0f = pp[p][0], y0f = pp[p][1];
        float wx1f = pp[p][2], wy1f = pp[p][3];
        float wx0f = 1.0f - wx1f, wy0f = 1.0f - wy1f;
        const float* img = feat + ((size_t)b * FCH + c) * FPX;
        float acc = 0.f;
#define TAPF(XC, YC, WV) { \
        float xf = (XC), yf = (YC); \
        float valid = (xf >= 0.f && xf <= 127.f && yf >= 0.f && yf <= 127.f) ? 1.f : 0.f; \
        int xi = (int)fminf(fmaxf(xf, 0.f), 127.f); \
        int yi = (int)fminf(fmaxf(yf, 0.f), 127.f); \
        acc += img[yi * 128 + xi] * ((WV) * valid); }
        TAPF(x0f,        y0f,        wx0f * wy0f)
        TAPF(x0f + 1.0f, y0f,        wx1f * wy0f)
        TAPF(x0f,        y0f + 1.0f, wx0f * wy1f)
        TAPF(x0f + 1.0f, y0f + 1.0f, wx1f * wy1f)
#undef TAPF
        Fl[p][c + 3] = acc;
    }
    __syncthreads();

    {   // layer 1: 515(+1 pad) -> 256, relu
        int o = tid;
        float acc[PB];
#pragma unroll
        for (int p = 0; p < PB; ++p) acc[p] = 0.f;
        for (int c4 = 0; c4 < FSTR / 4; ++c4) {
            float wa = wt1[(c4 * 4 + 0) * HID + o];
            float wb = wt1[(c4 * 4 + 1) * HID + o];
            float wc = wt1[(c4 * 4 + 2) * HID + o];
            float wd = wt1[(c4 * 4 + 3) * HID + o];
#pragma unroll
            for (int p = 0; p < PB; ++p) {
                float4 f = *(const float4*)&Fl[p][c4 * 4];
                acc[p] = fmaf(wa, f.x, acc[p]);
                acc[p] = fmaf(wb, f.y, acc[p]);
                acc[p] = fmaf(wc, f.z, acc[p]);
                acc[p] = fmaf(wd, f.w, acc[p]);
            }
        }
#pragma unroll
        for (int p = 0; p < PB; ++p) hA[p][o] = fmaxf(acc[p], 0.f);
    }
    __syncthreads();
    {   // layer 2
        int o = tid;
        float acc[PB];
#pragma unroll
        for (int p = 0; p < PB; ++p) acc[p] = 0.f;
        for (int c4 = 0; c4 < HID / 4; ++c4) {
            float wa = wt2[(c4 * 4 + 0) * HID + o];
            float wb = wt2[(c4 * 4 + 1) * HID + o];
            float wc = wt2[(c4 * 4 + 2) * HID + o];
            float wd = wt2[(c4 * 4 + 3) * HID + o];
#pragma unroll
            for (int p = 0; p < PB; ++p) {
                float4 f = *(const float4*)&hA[p][c4 * 4];
                acc[p] = fmaf(wa, f.x, acc[p]);
                acc[p] = fmaf(wb, f.y, acc[p]);
                acc[p] = fmaf(wc, f.z, acc[p]);
                acc[p] = fmaf(wd, f.w, acc[p]);
            }
        }
#pragma unroll
        for (int p = 0; p < PB; ++p) hB[p][o] = fmaxf(acc[p], 0.f);
    }
    __syncthreads();
    {   // layer 3
        int o = tid;
        float acc[PB];
#pragma unroll
        for (int p = 0; p < PB; ++p) acc[p] = 0.f;
        for (int c4 = 0; c4 < HID / 4; ++c4) {
            float wa = wt3[(c4 * 4 + 0) * HID + o];
            float wb = wt3[(c4 * 4 + 1) * HID + o];
            float wc = wt3[(c4 * 4 + 2) * HID + o];
            float wd = wt3[(c4 * 4 + 3) * HID + o];
#pragma unroll
            for (int p = 0; p < PB; ++p) {
                float4 f = *(const float4*)&hB[p][c4 * 4];
                acc[p] = fmaf(wa, f.x, acc[p]);
                acc[p] = fmaf(wb, f.y, acc[p]);
                acc[p] = fmaf(wc, f.z, acc[p]);
                acc[p] = fmaf(wd, f.w, acc[p]);
            }
        }
#pragma unroll
        for (int p = 0; p < PB; ++p) hA[p][o] = fmaxf(acc[p], 0.f);
    }
    __syncthreads();
    if (tid < 3 * PB) {  // layer 4: 256 -> 3, + b4
        int o = tid % 3, p = tid / 3;
        float acc = 0.f;
        const float* wr = w4 + (size_t)o * HID;
        for (int c = 0; c < HID; ++c) acc += wr[c] * hA[p][c];
        acc += b4[o];
        int gp = p0 + p;
        int b = gp / NP, n = gp % NP;
        rend[(size_t)b * (NCLS * NP) + o * NP + n] = acc;
    }
}

extern "C" void kernel_launch(void* const* d_in, const int* in_sizes, int n_in,
                              void* d_out, int out_size, void* d_ws, size_t ws_size,
                              hipStream_t stream) {
    // inputs: 0:x(unused) 1:feature 2:mask 3:over_gen 4:coverage 5:w1 6:w2 7:w3 8:w4 9:b4
    const float* feature  = (const float*)d_in[1];
    const float* mask     = (const float*)d_in[2];
    const float* over_gen = (const float*)d_in[3];
    const float* coverage = (const float*)d_in[4];
    const float* w1 = (const float*)d_in[5];
    const float* w2 = (const float*)d_in[6];
    const float* w3 = (const float*)d_in[7];
    const float* w4 = (const float*)d_in[8];
    const float* b4 = (const float*)d_in[9];
    float* out = (float*)d_out;
    float* ws  = (float*)d_ws;

    float* uws = ws + WS_U;
    float* pts = ws + WS_PTS;
    float* wt1 = ws + WS_WT1;
    float* wt2 = ws + WS_WT2;
    float* wt3 = ws + WS_WT3;

    // out layout: rend[4800] | points[3200] | mask[49152]
    float* out_rend = out;
    float* out_pts  = out + 4800;
    float* out_mask = out + 8000;

    k_front<<<GRID_FRONT, 1024, 0, stream>>>(mask, over_gen, coverage,
                                             w1, w2, w3,
                                             uws, pts, out_pts,
                                             wt1, wt2, wt3, out_mask);
    k_back<<<(B * NP) / PB, 256, 0, stream>>>(mask, feature, pts,
                                              wt1, wt2, wt3, w4, b4, out_rend);
}

// Round 4
// 146.648 us; speedup vs baseline: 2.6761x; 1.1773x over previous
//
#include <hip/hip_runtime.h>
#include <math.h>

#define B      16
#define KN     80000
#define MASKW  32
#define MASKPX 1024
#define NCLS   3
#define BN     95
#define NP     100
#define NCOV   5
#define FW     128
#define FCH    512
#define FPX    16384
#define CIN    515
#define FSTR   516
#define HID    256
#define NBIN   4096
#define CCAP   2048
#define PB     4

#define NTW    (FSTR*HID + HID*HID + HID*HID)   // 263168
#define NMASK  (B*NCLS*MASKPX)                  // 49152
#define PREP_TOT (NTW + NMASK)                  // 312320
#define SEL_B  16
#define PREP_BLOCKS 64
#define PREP_STRIDE (PREP_BLOCKS * 1024)
#define GRID_FRONT (SEL_B + PREP_BLOCKS)

// ---- ws layout (float offsets) ----
#define WS_U   0
#define WS_PTS (WS_U + B*KN)
#define WS_WT1 (WS_PTS + B*NP*2)
#define WS_WT2 (WS_WT1 + FSTR*HID)
#define WS_WT3 (WS_WT2 + HID*HID)

// K_FRONT: blocks 0..15 = fused per-batch point selection
//          blocks 16..79 = grid-stride weight transpose + mask passthrough
__global__ __launch_bounds__(1024) void k_front(
        const float* __restrict__ mask, const float* __restrict__ og,
        const float* __restrict__ cov,
        const float* __restrict__ w1, const float* __restrict__ w2,
        const float* __restrict__ w3,
        float* __restrict__ uws, float* __restrict__ pts_ws,
        float* __restrict__ pts_out,
        float* __restrict__ wt1, float* __restrict__ wt2, float* __restrict__ wt3,
        float* __restrict__ out_mask) {
    __shared__ float ps0[MASKPX];
    __shared__ float ps1[MASKPX];
    __shared__ int   hist[NBIN];
    __shared__ float cv[CCAP];
    __shared__ int   ci[CCAP];
    __shared__ int   s_cnt;
    __shared__ float s_T;
    int tid = threadIdx.x;

    if (blockIdx.x >= SEL_B) {
        // ---- prep path: grid-stride elementwise ----
        for (int j0 = (blockIdx.x - SEL_B) * 1024 + tid; j0 < PREP_TOT;
             j0 += PREP_STRIDE) {
            int j = j0;
            if (j < FSTR * HID) {
                int c = j >> 8, o = j & 255;
                wt1[j] = (c < CIN) ? w1[o * CIN + c] : 0.0f;
                continue;
            }
            j -= FSTR * HID;
            if (j < HID * HID) {
                int c = j >> 8, o = j & 255;
                wt2[j] = w2[o * HID + c];
                continue;
            }
            j -= HID * HID;
            if (j < HID * HID) {
                int c = j >> 8, o = j & 255;
                wt3[j] = w3[o * HID + c];
                continue;
            }
            j -= HID * HID;
            out_mask[j] = mask[j];
        }
        return;
    }

    // ---- select path, batch b ----
    int b = blockIdx.x;
    // softmax top-2 into LDS (identical fp op sequence to prior rounds)
    for (int pix = tid; pix < MASKPX; pix += 1024) {
        const float* mb = mask + (size_t)b * NCLS * MASKPX + pix;
        float a0 = mb[0], a1 = mb[MASKPX], a2 = mb[2 * MASKPX];
        float m = fmaxf(fmaxf(a0, a1), a2);
        float e0 = (float)exp((double)(a0 - m));
        float e1 = (float)exp((double)(a1 - m));
        float e2 = (float)exp((double)(a2 - m));
        float s = (e0 + e1) + e2;
        float p0 = e0 / s, p1 = e1 / s, p2 = e2 / s;
        float hi  = fmaxf(fmaxf(p0, p1), p2);
        float mid = fmaxf(fminf(p0, p1), fminf(fmaxf(p0, p1), p2));
        ps0[pix] = hi;
        ps1[pix] = mid;
    }
    for (int i = tid; i < NBIN; i += 1024) hist[i] = 0;
    if (tid == 0) s_cnt = 0;
    __syncthreads();

    // u + histogram pass (u op sequence identical to prior rounds)
    float* ub = uws + (size_t)b * KN;
    const float2* ogb = (const float2*)(og + (size_t)b * KN * 2);
    for (int i = tid; i < KN; i += 1024) {
        float2 q = ogb[i];
        float cx = q.x, cy = q.y;
        float gx = 2.0f * cx - 1.0f, gy = 2.0f * cy - 1.0f;
        float ix = ((gx + 1.0f) * 32.0f - 1.0f) * 0.5f;
        float iy = ((gy + 1.0f) * 32.0f - 1.0f) * 0.5f;
        float x0 = floorf(ix), y0 = floorf(iy);
        float wx1 = ix - x0, wy1 = iy - y0;
        float wx0 = 1.0f - wx1, wy0 = 1.0f - wy1;
        float s0 = 0.f, s1 = 0.f;
#define TAP(XC, YC, WV) { \
        float xf = (XC), yf = (YC); \
        float valid = (xf >= 0.f && xf <= 31.f && yf >= 0.f && yf <= 31.f) ? 1.f : 0.f; \
        int xi = (int)fminf(fmaxf(xf, 0.f), 31.f); \
        int yi = (int)fminf(fmaxf(yf, 0.f), 31.f); \
        float w = (WV) * valid; \
        int off = yi * 32 + xi; \
        s0 += ps0[off] * w; s1 += ps1[off] * w; }
        TAP(x0,        y0,        wx0 * wy0)
        TAP(x0 + 1.0f, y0,        wx1 * wy0)
        TAP(x0,        y0 + 1.0f, wx0 * wy1)
        TAP(x0 + 1.0f, y0 + 1.0f, wx1 * wy1)
#undef TAP
        float v = -(s0 - s1);
        ub[i] = v;
        int bin = (int)((v + 1.0f) * 4096.0f);
        bin = bin < 0 ? 0 : (bin > NBIN - 1 ? NBIN - 1 : bin);
        atomicAdd(&hist[bin], 1);
    }
    __syncthreads();

    // two-level wave-parallel suffix scan to find threshold bin tb
    if (tid < 64) {
        int sup = 0;
#pragma unroll
        for (int j = 0; j < 64; ++j) sup += hist[(tid << 6) + j];
        int cum = sup;
#pragma unroll
        for (int d = 1; d < 64; d <<= 1) {
            int o = __shfl_down(cum, d, 64);
            if (tid + d < 64) cum += o;
        }
        unsigned long long m1 = __ballot(cum >= BN);
        int SB = 63 - __builtin_clzll(m1);
        int lane2 = (SB + 1) & 63;
        int above = __shfl(cum, lane2, 64);
        if (SB == 63) above = 0;
        int h = hist[(SB << 6) + tid];
        int cumf = h;
#pragma unroll
        for (int d = 1; d < 64; d <<= 1) {
            int o = __shfl_down(cumf, d, 64);
            if (tid + d < 64) cumf += o;
        }
        unsigned long long m2 = __ballot(cumf + above >= BN);
        int t = 63 - __builtin_clzll(m2);
        int tb = (SB << 6) + t;
        if (tid == 0)
            s_T = (tb > 0) ? ((float)(tb - 1) * (1.0f / 4096.0f) - 1.0f) : -2.0f;
    }
    __syncthreads();

    // collect candidates >= T (u re-read, L2-hot)
    float T = s_T;
    for (int i = tid; i < KN; i += 1024) {
        float v = ub[i];
        if (v >= T) {
            int pos = atomicAdd(&s_cnt, 1);
            if (pos < CCAP) { cv[pos] = v; ci[pos] = i; }
        }
    }
    __syncthreads();
    int n = s_cnt; if (n > CCAP) n = CCAP;
    int M = 128; while (M < n) M <<= 1;
    for (int i = tid; i < M; i += 1024)
        if (i >= n) { cv[i] = -3.0f; ci[i] = 0x7fffffff; }
    __syncthreads();
    // bitonic sort: descending by (value, then lower index first)
    for (int k = 2; k <= M; k <<= 1) {
        for (int j = k >> 1; j > 0; j >>= 1) {
            for (int idx = tid; idx < M; idx += 1024) {
                int l = idx ^ j;
                if (l > idx) {
                    float va = cv[idx], vb = cv[l];
                    int ia = ci[idx], ib = ci[l];
                    bool l_first = (vb > va) || (vb == va && ib < ia);
                    bool dirDesc = ((idx & k) == 0);
                    if (l_first == dirDesc) {
                        cv[idx] = vb; cv[l] = va;
                        ci[idx] = ib; ci[l] = ia;
                    }
                }
            }
            __syncthreads();
        }
    }
    if (tid < BN) {
        int gi = ci[tid];
        float px = og[((size_t)b * KN + gi) * 2];
        float py = og[((size_t)b * KN + gi) * 2 + 1];
        int o = (b * NP + tid) * 2;
        pts_ws[o] = px; pts_ws[o + 1] = py;
        pts_out[o] = px; pts_out[o + 1] = py;
    } else if (tid < NP) {
        int j = tid - BN;
        float px = cov[((size_t)b * NCOV + j) * 2];
        float py = cov[((size_t)b * NCOV + j) * 2 + 1];
        int o = (b * NP + tid) * 2;
        pts_ws[o] = px; pts_ws[o + 1] = py;
        pts_out[o] = px; pts_out[o + 1] = py;
    }
}

// K_BACK: fused gather (coarse from mask, fine from feature) + 4-layer MLP.
// PB=4 points/block, 400 blocks for TLP.
__global__ __launch_bounds__(256) void k_back(
        const float* __restrict__ maskp, const float* __restrict__ feat,
        const float* __restrict__ pts,
        const float* __restrict__ wt1, const float* __restrict__ wt2,
        const float* __restrict__ wt3, const float* __restrict__ w4,
        const float* __restrict__ b4, float* __restrict__ rend) {
    __shared__ float Fl[PB][FSTR];
    __shared__ float hA[PB][HID];
    __shared__ float hB[PB][HID];
    __shared__ float pp[PB][8];
    int tid = threadIdx.x;
    int p0 = blockIdx.x * PB;

    if (tid < PB) {   // per-point sampling params
        int gp = p0 + tid;
        float cx = pts[(size_t)gp * 2], cy = pts[(size_t)gp * 2 + 1];
        float gx = 2.0f * cx - 1.0f, gy = 2.0f * cy - 1.0f;
        float ixf = ((gx + 1.0f) * 128.0f - 1.0f) * 0.5f;
        float iyf = ((gy + 1.0f) * 128.0f - 1.0f) * 0.5f;
        float x0f = floorf(ixf), y0f = floorf(iyf);
        pp[tid][0] = x0f; pp[tid][1] = y0f;
        pp[tid][2] = ixf - x0f; pp[tid][3] = iyf - y0f;
        float ixm = ((gx + 1.0f) * 32.0f - 1.0f) * 0.5f;
        float iym = ((gy + 1.0f) * 32.0f - 1.0f) * 0.5f;
        float x0m = floorf(ixm), y0m = floorf(iym);
        pp[tid][4] = x0m; pp[tid][5] = y0m;
        pp[tid][6] = ixm - x0m; pp[tid][7] = iym - y0m;
    }
    __syncthreads();

    if (tid < PB * 4) {   // coarse channels + pad
        int p = tid >> 2, c = tid & 3;
        if (c < 3) {
            int gp = p0 + p, b = gp / NP;
            float x0m = pp[p][4], y0m = pp[p][5];
            float wx1m = pp[p][6], wy1m = pp[p][7];
            float wx0m = 1.0f - wx1m, wy0m = 1.0f - wy1m;
            const float* img = maskp + ((size_t)b * NCLS + c) * MASKPX;
            float acc = 0.f;
#define TAPM(XC, YC, WV) { \
            float xf = (XC), yf = (YC); \
            float valid = (xf >= 0.f && xf <= 31.f && yf >= 0.f && yf <= 31.f) ? 1.f : 0.f; \
            int xi = (int)fminf(fmaxf(xf, 0.f), 31.f); \
            int yi = (int)fminf(fmaxf(yf, 0.f), 31.f); \
            acc += img[yi * 32 + xi] * ((WV) * valid); }
            TAPM(x0m,        y0m,        wx0m * wy0m)
            TAPM(x0m + 1.0f, y0m,        wx1m * wy0m)
            TAPM(x0m,        y0m + 1.0f, wx0m * wy1m)
            TAPM(x0m + 1.0f, y0m + 1.0f, wx1m * wy1m)
#undef TAPM
            Fl[p][c] = acc;
        } else {
            Fl[p][CIN] = 0.0f;   // pad channel
        }
    }

    // fine channels: 4 pts x 512 ch = 8 per thread, 4 independent loads each
#pragma unroll 4
    for (int i = tid; i < PB * FCH; i += 256) {
        int p = i >> 9, c = i & 511;
        int gp = p0 + p, b = gp / NP;
        float x0f = pp[p][0], y0f = pp[p][1];
        float wx1f = pp[p][2], wy1f = pp[p][3];
        float wx0f = 1.0f - wx1f, wy0f = 1.0f - wy1f;
        const float* img = feat + ((size_t)b * FCH + c) * FPX;
        float acc = 0.f;
#define TAPF(XC, YC, WV) { \
        float xf = (XC), yf = (YC); \
        float valid = (xf >= 0.f && xf <= 127.f && yf >= 0.f && yf <= 127.f) ? 1.f : 0.f; \
        int xi = (int)fminf(fmaxf(xf, 0.f), 127.f); \
        int yi = (int)fminf(fmaxf(yf, 0.f), 127.f); \
        acc += img[yi * 128 + xi] * ((WV) * valid); }
        TAPF(x0f,        y0f,        wx0f * wy0f)
        TAPF(x0f + 1.0f, y0f,        wx1f * wy0f)
        TAPF(x0f,        y0f + 1.0f, wx0f * wy1f)
        TAPF(x0f + 1.0f, y0f + 1.0f, wx1f * wy1f)
#undef TAPF
        Fl[p][c + 3] = acc;
    }
    __syncthreads();

    {   // layer 1: 515(+1 pad) -> 256, relu
        int o = tid;
        float acc[PB];
#pragma unroll
        for (int p = 0; p < PB; ++p) acc[p] = 0.f;
        for (int c4 = 0; c4 < FSTR / 4; ++c4) {
            float wa = wt1[(c4 * 4 + 0) * HID + o];
            float wb = wt1[(c4 * 4 + 1) * HID + o];
            float wc = wt1[(c4 * 4 + 2) * HID + o];
            float wd = wt1[(c4 * 4 + 3) * HID + o];
#pragma unroll
            for (int p = 0; p < PB; ++p) {
                float4 f = *(const float4*)&Fl[p][c4 * 4];
                acc[p] = fmaf(wa, f.x, acc[p]);
                acc[p] = fmaf(wb, f.y, acc[p]);
                acc[p] = fmaf(wc, f.z, acc[p]);
                acc[p] = fmaf(wd, f.w, acc[p]);
            }
        }
#pragma unroll
        for (int p = 0; p < PB; ++p) hA[p][o] = fmaxf(acc[p], 0.f);
    }
    __syncthreads();
    {   // layer 2
        int o = tid;
        float acc[PB];
#pragma unroll
        for (int p = 0; p < PB; ++p) acc[p] = 0.f;
        for (int c4 = 0; c4 < HID / 4; ++c4) {
            float wa = wt2[(c4 * 4 + 0) * HID + o];
            float wb = wt2[(c4 * 4 + 1) * HID + o];
            float wc = wt2[(c4 * 4 + 2) * HID + o];
            float wd = wt2[(c4 * 4 + 3) * HID + o];
#pragma unroll
            for (int p = 0; p < PB; ++p) {
                float4 f = *(const float4*)&hA[p][c4 * 4];
                acc[p] = fmaf(wa, f.x, acc[p]);
                acc[p] = fmaf(wb, f.y, acc[p]);
                acc[p] = fmaf(wc, f.z, acc[p]);
                acc[p] = fmaf(wd, f.w, acc[p]);
            }
        }
#pragma unroll
        for (int p = 0; p < PB; ++p) hB[p][o] = fmaxf(acc[p], 0.f);
    }
    __syncthreads();
    {   // layer 3
        int o = tid;
        float acc[PB];
#pragma unroll
        for (int p = 0; p < PB; ++p) acc[p] = 0.f;
        for (int c4 = 0; c4 < HID / 4; ++c4) {
            float wa = wt3[(c4 * 4 + 0) * HID + o];
            float wb = wt3[(c4 * 4 + 1) * HID + o];
            float wc = wt3[(c4 * 4 + 2) * HID + o];
            float wd = wt3[(c4 * 4 + 3) * HID + o];
#pragma unroll
            for (int p = 0; p < PB; ++p) {
                float4 f = *(const float4*)&hB[p][c4 * 4];
                acc[p] = fmaf(wa, f.x, acc[p]);
                acc[p] = fmaf(wb, f.y, acc[p]);
                acc[p] = fmaf(wc, f.z, acc[p]);
                acc[p] = fmaf(wd, f.w, acc[p]);
            }
        }
#pragma unroll
        for (int p = 0; p < PB; ++p) hA[p][o] = fmaxf(acc[p], 0.f);
    }
    __syncthreads();
    if (tid < 3 * PB) {  // layer 4: 256 -> 3, + b4
        int o = tid % 3, p = tid / 3;
        float acc = 0.f;
        const float* wr = w4 + (size_t)o * HID;
        for (int c = 0; c < HID; ++c) acc += wr[c] * hA[p][c];
        acc += b4[o];
        int gp = p0 + p;
        int b = gp / NP, n = gp % NP;
        rend[(size_t)b * (NCLS * NP) + o * NP + n] = acc;
    }
}

extern "C" void kernel_launch(void* const* d_in, const int* in_sizes, int n_in,
                              void* d_out, int out_size, void* d_ws, size_t ws_size,
                              hipStream_t stream) {
    // inputs: 0:x(unused) 1:feature 2:mask 3:over_gen 4:coverage 5:w1 6:w2 7:w3 8:w4 9:b4
    const float* feature  = (const float*)d_in[1];
    const float* mask     = (const float*)d_in[2];
    const float* over_gen = (const float*)d_in[3];
    const float* coverage = (const float*)d_in[4];
    const float* w1 = (const float*)d_in[5];
    const float* w2 = (const float*)d_in[6];
    const float* w3 = (const float*)d_in[7];
    const float* w4 = (const float*)d_in[8];
    const float* b4 = (const float*)d_in[9];
    float* out = (float*)d_out;
    float* ws  = (float*)d_ws;

    float* uws = ws + WS_U;
    float* pts = ws + WS_PTS;
    float* wt1 = ws + WS_WT1;
    float* wt2 = ws + WS_WT2;
    float* wt3 = ws + WS_WT3;

    // out layout: rend[4800] | points[3200] | mask[49152]
    float* out_rend = out;
    float* out_pts  = out + 4800;
    float* out_mask = out + 8000;

    k_front<<<GRID_FRONT, 1024, 0, stream>>>(mask, over_gen, coverage,
                                             w1, w2, w3,
                                             uws, pts, out_pts,
                                             wt1, wt2, wt3, out_mask);
    k_back<<<(B * NP) / PB, 256, 0, stream>>>(mask, feature, pts,
                                              wt1, wt2, wt3, w4, b4, out_rend);
}